// Round 2
// baseline (247.469 us; speedup 1.0000x reference)
//
#include <hip/hip_runtime.h>

#define NB   32
#define LSEQ 4096
#define DM   512

// db4 decomposition low-pass; DEC_HI[k] = (-1)^(k+1) * DEC_LO[7-k]
__device__ __constant__ float c_DL[8] = {
    -0.010597401784997278f,  0.032883011666982945f,  0.030841381835986965f,
    -0.18703481171888114f,  -0.02798376941698385f,   0.6308807679295904f,
     0.7148465705525415f,    0.23037781330885523f};
__device__ __constant__ float c_DH[8] = {
    -0.23037781330885523f,   0.7148465705525415f,   -0.6308807679295904f,
    -0.02798376941698385f,   0.18703481171888114f,   0.030841381835986965f,
    -0.032883011666982945f, -0.010597401784997278f};

// workspace layout (floats)
#define S_OFF     0
#define GATES_OFF (5 * NB * LSEQ)                 // 655360
#define COEF_OFF  (GATES_OFF + 5 * DM)            // 657920
#define L4_OFF    (COEF_OFF)                      // 32 x 262
#define H4_OFF    (L4_OFF + NB * 262)
#define H3_OFF    (H4_OFF + NB * 262)             // 32 x 518
#define H2_OFF    (H3_OFF + NB * 518)             // 32 x 1029
#define H1_OFF    (H2_OFF + NB * 1029)            // 32 x 2051

__device__ __forceinline__ int reflect_idx(int i, int N) {
    if (i < 0)  i = -1 - i;
    if (i >= N) i = 2 * N - 1 - i;
    return i;
}

// Forward DWT step: symmetric pad (padL=6 at every level) + stride-2 corr.
// lo -> LDS, hi -> global coeff array.
__device__ void fwd_step(const float* __restrict__ src, int N,
                         float* __restrict__ lo, float* __restrict__ hi) {
    int outsize = (N + 7) >> 1;
    int p = 2 * (outsize - 1) - N + 8;
    int padL = p >> 1;
    for (int t = threadIdx.x; t < outsize; t += blockDim.x) {
        int base = 2 * t - padL;
        float aL = 0.f, aH = 0.f;
#pragma unroll
        for (int k = 0; k < 8; ++k) {
            float xv = src[reflect_idx(base + k, N)];
            aL = fmaf(xv, c_DL[7 - k], aL);
            aH = fmaf(xv, c_DH[7 - k], aH);
        }
        lo[t] = aL;
        hi[t] = aH;
    }
}

// Inverse DWT step: lhs_dilation=2, pad (1,1), VALID corr with filter F.
// y[t] = sum_{j=0..3} c[(t>>1)+j] * F[2j+1-(t&1)], outN = 2n-6 (all in-range)
__device__ void inv_step(const float* __restrict__ c, int n,
                         float* __restrict__ y, const float* __restrict__ F) {
    int outN = 2 * n - 6;
    for (int t = threadIdx.x; t < outN; t += blockDim.x) {
        int base = t >> 1;
        int odd = t & 1;
        float acc = c[base] * F[1 - odd];
        acc = fmaf(c[base + 1], F[3 - odd], acc);
        acc = fmaf(c[base + 2], F[5 - odd], acc);
        acc = fmaf(c[base + 3], F[7 - odd], acc);
        y[t] = acc;
    }
}

// Blocks 0..31: projection + 4 forward levels for batch b (coeffs -> ws).
// Blocks 32..34: gates (5x512 dual dot + sigmoid*tanh).
__global__ __launch_bounds__(1024) void fwd_gates_kernel(
    const float* __restrict__ x, const float* __restrict__ proj_w,
    const float* __restrict__ proj_b, const float* __restrict__ scale_emb,
    const float* __restrict__ gate_w, const float* __restrict__ gate_b,
    float* __restrict__ ws) {
    if (blockIdx.x >= NB) {
        int q = (blockIdx.x - NB) * 1024 + threadIdx.x;
        if (q >= 5 * DM) return;
        int j = q >> 9, c = q & (DM - 1);
        const float4* se = (const float4*)(scale_emb + (size_t)j * DM);
        const float4* g0 = (const float4*)(gate_w + (size_t)c * DM);
        const float4* g1 = (const float4*)(gate_w + (size_t)(DM + c) * DM);
        float ag = 0.f, av = 0.f;
#pragma unroll 4
        for (int i = 0; i < DM / 4; ++i) {
            float4 s = se[i], a = g0[i], bq = g1[i];
            ag = fmaf(s.x, a.x, ag);  ag = fmaf(s.y, a.y, ag);
            ag = fmaf(s.z, a.z, ag);  ag = fmaf(s.w, a.w, ag);
            av = fmaf(s.x, bq.x, av); av = fmaf(s.y, bq.y, av);
            av = fmaf(s.z, bq.z, av); av = fmaf(s.w, bq.w, av);
        }
        ag += gate_b[c];
        av += gate_b[DM + c];
        float sg = 1.f / (1.f + expf(-ag));
        ws[GATES_OFF + q] = sg * tanhf(av);
        return;
    }

    __shared__ float A[4096];
    __shared__ float Bb[2052];
    int b = blockIdx.x;

    float w[8];
#pragma unroll
    for (int k = 0; k < 8; ++k) w[k] = proj_w[k];
    float pb = proj_b[0];

    const float* xb = x + (size_t)b * LSEQ * 8;
    for (int l = threadIdx.x; l < LSEQ; l += blockDim.x) {
        const float4* xv = (const float4*)(xb + (size_t)l * 8);
        float4 a0 = xv[0], a1 = xv[1];
        float acc = pb;
        acc = fmaf(a0.x, w[0], acc); acc = fmaf(a0.y, w[1], acc);
        acc = fmaf(a0.z, w[2], acc); acc = fmaf(a0.w, w[3], acc);
        acc = fmaf(a1.x, w[4], acc); acc = fmaf(a1.y, w[5], acc);
        acc = fmaf(a1.z, w[6], acc); acc = fmaf(a1.w, w[7], acc);
        A[l] = acc;
    }
    __syncthreads();

    // 4096 -> 2051 -> 1029 -> 518 -> 262; hi coeffs straight to ws
    fwd_step(A, 4096, Bb, ws + H1_OFF + b * 2051);  __syncthreads();
    fwd_step(Bb, 2051, A, ws + H2_OFF + b * 1029);  __syncthreads();
    fwd_step(A, 1029, Bb, ws + H3_OFF + b * 518);   __syncthreads();
    fwd_step(Bb, 518, ws + L4_OFF + b * 262, ws + H4_OFF + b * 262);
}

// One block per (batch, level) chain: 32*5 = 160 independent IDWT chains.
__global__ __launch_bounds__(1024) void inv_kernel(float* __restrict__ ws) {
    __shared__ float A[4096];
    __shared__ float Bb[2052];
    int q = blockIdx.x;
    int b = q / 5;
    int j = q % 5;

    const float* src;
    int n0;
    switch (j) {
        case 0: src = ws + L4_OFF + b * 262;  n0 = 262;  break;
        case 4: src = ws + H4_OFF + b * 262;  n0 = 262;  break;
        case 3: src = ws + H3_OFF + b * 518;  n0 = 518;  break;
        case 2: src = ws + H2_OFF + b * 1029; n0 = 1029; break;
        default: src = ws + H1_OFF + b * 2051; n0 = 2051; break;
    }
    for (int i = threadIdx.x; i < n0; i += blockDim.x) Bb[i] = src[i];
    __syncthreads();

    float* Sb = ws + S_OFF + (size_t)j * NB * LSEQ + (size_t)b * LSEQ;
    const float* F = (j == 0) ? c_DL : c_DH;
    float* cur = Bb;
    float* nxt = A;
    int n = n0;
    while (true) {
        int outN = 2 * n - 6;
        if (outN == 4096) { inv_step(cur, n, Sb, F); break; }
        inv_step(cur, n, nxt, F);
        __syncthreads();
        n = (outN == 1030) ? 1029 : (outN == 2052) ? 2051 : outN;
        float* t = cur; cur = nxt; nxt = t;
        F = c_DL;
    }
}

// pe[b,l,c] = sum_j gates[j][c] * S[j][b*L+l]. Pure write-BW kernel.
__global__ __launch_bounds__(256) void expand_kernel(
    const float* __restrict__ ws, float* __restrict__ out) {
    const float* S = ws + S_OFF;
    const float* gates = ws + GATES_OFF;
    __shared__ float gl[5 * DM];
    for (int i = threadIdx.x; i < 5 * DM / 4; i += 256)
        ((float4*)gl)[i] = ((const float4*)gates)[i];
    __syncthreads();

    const size_t BL = (size_t)NB * LSEQ;
    int half = threadIdx.x >> 7;       // 0/1: which row of the pair
    int c4 = threadIdx.x & 127;        // float4 index over 512 channels
    float4 g0 = ((const float4*)(gl + 0 * DM))[c4];
    float4 g1 = ((const float4*)(gl + 1 * DM))[c4];
    float4 g2 = ((const float4*)(gl + 2 * DM))[c4];
    float4 g3 = ((const float4*)(gl + 3 * DM))[c4];
    float4 g4 = ((const float4*)(gl + 4 * DM))[c4];

    int rowBase = blockIdx.x * 32;
#pragma unroll 4
    for (int r = 0; r < 16; ++r) {
        int row = rowBase + r * 2 + half;
        float s0 = S[row];
        float s1 = S[BL + row];
        float s2 = S[2 * BL + row];
        float s3 = S[3 * BL + row];
        float s4 = S[4 * BL + row];
        float4 acc;
        acc.x = fmaf(s4, g4.x, fmaf(s3, g3.x, fmaf(s2, g2.x, fmaf(s1, g1.x, s0 * g0.x))));
        acc.y = fmaf(s4, g4.y, fmaf(s3, g3.y, fmaf(s2, g2.y, fmaf(s1, g1.y, s0 * g0.y))));
        acc.z = fmaf(s4, g4.z, fmaf(s3, g3.z, fmaf(s2, g2.z, fmaf(s1, g1.z, s0 * g0.z))));
        acc.w = fmaf(s4, g4.w, fmaf(s3, g3.w, fmaf(s2, g2.w, fmaf(s1, g1.w, s0 * g0.w))));
        ((float4*)out)[(size_t)row * (DM / 4) + c4] = acc;
    }
}

extern "C" void kernel_launch(void* const* d_in, const int* in_sizes, int n_in,
                              void* d_out, int out_size, void* d_ws, size_t ws_size,
                              hipStream_t stream) {
    const float* x         = (const float*)d_in[0];
    const float* proj_w    = (const float*)d_in[1];
    const float* proj_b    = (const float*)d_in[2];
    const float* scale_emb = (const float*)d_in[3];
    const float* gate_w    = (const float*)d_in[4];
    const float* gate_b    = (const float*)d_in[5];
    float* out = (float*)d_out;
    float* ws  = (float*)d_ws;

    fwd_gates_kernel<<<NB + 3, 1024, 0, stream>>>(x, proj_w, proj_b,
                                                  scale_emb, gate_w, gate_b, ws);
    inv_kernel<<<NB * 5, 1024, 0, stream>>>(ws);
    expand_kernel<<<(NB * LSEQ) / 32, 256, 0, stream>>>(ws, out);
}

// Round 3
// 111.837 us; speedup vs baseline: 2.2128x; 2.2128x over previous
//
#include <hip/hip_runtime.h>

#define NB   32
#define LSEQ 4096
#define DM   512

// db4 decomposition low-pass; DEC_HI[k] = (-1)^(k+1) * DEC_LO[7-k]
__device__ __constant__ float c_DL[8] = {
    -0.010597401784997278f,  0.032883011666982945f,  0.030841381835986965f,
    -0.18703481171888114f,  -0.02798376941698385f,   0.6308807679295904f,
     0.7148465705525415f,    0.23037781330885523f};
__device__ __constant__ float c_DH[8] = {
    -0.23037781330885523f,   0.7148465705525415f,   -0.6308807679295904f,
    -0.02798376941698385f,   0.18703481171888114f,   0.030841381835986965f,
    -0.032883011666982945f, -0.010597401784997278f};

// workspace layout (floats)
#define S_OFF     0
#define GATES_OFF (5 * NB * LSEQ)                 // 655360
#define COEF_OFF  (GATES_OFF + 5 * DM)            // 657920
#define L4_OFF    (COEF_OFF)                      // 32 x 262
#define H4_OFF    (L4_OFF + NB * 262)
#define H3_OFF    (H4_OFF + NB * 262)             // 32 x 518
#define H2_OFF    (H3_OFF + NB * 518)             // 32 x 1029
#define H1_OFF    (H2_OFF + NB * 1029)            // 32 x 2051

__device__ __forceinline__ int reflect_idx(int i, int N) {
    if (i < 0)  i = -1 - i;
    if (i >= N) i = 2 * N - 1 - i;
    return i;
}

// Forward DWT step: symmetric pad (padL=6 at every level) + stride-2 corr.
__device__ void fwd_step(const float* __restrict__ src, int N,
                         float* __restrict__ lo, float* __restrict__ hi) {
    int outsize = (N + 7) >> 1;
    int p = 2 * (outsize - 1) - N + 8;
    int padL = p >> 1;
    for (int t = threadIdx.x; t < outsize; t += blockDim.x) {
        int base = 2 * t - padL;
        float aL = 0.f, aH = 0.f;
#pragma unroll
        for (int k = 0; k < 8; ++k) {
            float xv = src[reflect_idx(base + k, N)];
            aL = fmaf(xv, c_DL[7 - k], aL);
            aH = fmaf(xv, c_DH[7 - k], aH);
        }
        lo[t] = aL;
        hi[t] = aH;
    }
}

// Inverse DWT step: lhs_dilation=2, pad (1,1), VALID corr. Compile-time filter.
// y[t] = sum_{j=0..3} c[(t>>1)+j] * F[2j+1-(t&1)], outN = 2n-6 (all in-range)
template <bool HI>
__device__ void inv_step(const float* __restrict__ c, int n, float* __restrict__ y) {
    int outN = 2 * n - 6;
    for (int t = threadIdx.x; t < outN; t += blockDim.x) {
        int base = t >> 1;
        int odd = t & 1;
        float f0 = odd ? (HI ? c_DH[0] : c_DL[0]) : (HI ? c_DH[1] : c_DL[1]);
        float f1 = odd ? (HI ? c_DH[2] : c_DL[2]) : (HI ? c_DH[3] : c_DL[3]);
        float f2 = odd ? (HI ? c_DH[4] : c_DL[4]) : (HI ? c_DH[5] : c_DL[5]);
        float f3 = odd ? (HI ? c_DH[6] : c_DL[6]) : (HI ? c_DH[7] : c_DL[7]);
        float acc = c[base] * f0;
        acc = fmaf(c[base + 1], f1, acc);
        acc = fmaf(c[base + 2], f2, acc);
        acc = fmaf(c[base + 3], f3, acc);
        y[t] = acc;
    }
}

// One block per batch: projection + 4 forward levels (coeffs -> ws).
__global__ __launch_bounds__(1024) void fwd_kernel(
    const float* __restrict__ x, const float* __restrict__ proj_w,
    const float* __restrict__ proj_b, float* __restrict__ ws) {
    __shared__ float A[4096];
    __shared__ float Bb[2052];
    int b = blockIdx.x;

    float w[8];
#pragma unroll
    for (int k = 0; k < 8; ++k) w[k] = proj_w[k];
    float pb = proj_b[0];

    const float* xb = x + (size_t)b * LSEQ * 8;
    for (int l = threadIdx.x; l < LSEQ; l += blockDim.x) {
        const float4* xv = (const float4*)(xb + (size_t)l * 8);
        float4 a0 = xv[0], a1 = xv[1];
        float acc = pb;
        acc = fmaf(a0.x, w[0], acc); acc = fmaf(a0.y, w[1], acc);
        acc = fmaf(a0.z, w[2], acc); acc = fmaf(a0.w, w[3], acc);
        acc = fmaf(a1.x, w[4], acc); acc = fmaf(a1.y, w[5], acc);
        acc = fmaf(a1.z, w[6], acc); acc = fmaf(a1.w, w[7], acc);
        A[l] = acc;
    }
    __syncthreads();

    // 4096 -> 2051 -> 1029 -> 518 -> 262; hi coeffs straight to ws
    fwd_step(A, 4096, Bb, ws + H1_OFF + b * 2051);  __syncthreads();
    fwd_step(Bb, 2051, A, ws + H2_OFF + b * 1029);  __syncthreads();
    fwd_step(A, 1029, Bb, ws + H3_OFF + b * 518);   __syncthreads();
    fwd_step(Bb, 518, ws + L4_OFF + b * 262, ws + H4_OFF + b * 262);
}

// One wave per channel c: coalesced rows gw[c], gw[c+512]; 5 g-dots + 5 v-dots;
// shuffle-reduce; lane 0 writes gates[j][c] = sigmoid(g)*tanh(v).
__global__ __launch_bounds__(256) void gates_kernel(
    const float* __restrict__ scale_emb, const float* __restrict__ gate_w,
    const float* __restrict__ gate_b, float* __restrict__ gates) {
    int wave = (blockIdx.x * 256 + threadIdx.x) >> 6;   // 0..511 == channel c
    int lane = threadIdx.x & 63;
    int c = wave;
    const float4* rg = (const float4*)(gate_w + (size_t)c * DM) + lane * 2;
    const float4* rv = (const float4*)(gate_w + (size_t)(c + DM) * DM) + lane * 2;
    float4 a0 = rg[0], a1 = rg[1];
    float4 b0 = rv[0], b1 = rv[1];

    float gacc[5], vacc[5];
#pragma unroll
    for (int j = 0; j < 5; ++j) {
        const float4* sj = (const float4*)(scale_emb + (size_t)j * DM) + lane * 2;
        float4 s0 = sj[0], s1 = sj[1];
        float ga;
        ga = s0.x * a0.x;            ga = fmaf(s0.y, a0.y, ga);
        ga = fmaf(s0.z, a0.z, ga);   ga = fmaf(s0.w, a0.w, ga);
        ga = fmaf(s1.x, a1.x, ga);   ga = fmaf(s1.y, a1.y, ga);
        ga = fmaf(s1.z, a1.z, ga);   ga = fmaf(s1.w, a1.w, ga);
        float va;
        va = s0.x * b0.x;            va = fmaf(s0.y, b0.y, va);
        va = fmaf(s0.z, b0.z, va);   va = fmaf(s0.w, b0.w, va);
        va = fmaf(s1.x, b1.x, va);   va = fmaf(s1.y, b1.y, va);
        va = fmaf(s1.z, b1.z, va);   va = fmaf(s1.w, b1.w, va);
        gacc[j] = ga;
        vacc[j] = va;
    }
#pragma unroll
    for (int j = 0; j < 5; ++j) {
#pragma unroll
        for (int off = 32; off > 0; off >>= 1) {
            gacc[j] += __shfl_xor(gacc[j], off, 64);
            vacc[j] += __shfl_xor(vacc[j], off, 64);
        }
    }
    if (lane == 0) {
        float bg = gate_b[c], bv = gate_b[DM + c];
#pragma unroll
        for (int j = 0; j < 5; ++j) {
            float g = gacc[j] + bg;
            float v = vacc[j] + bv;
            float sg = 1.f / (1.f + expf(-g));
            gates[j * DM + c] = sg * tanhf(v);
        }
    }
}

// One block per (batch, level) chain: 32*5 = 160 independent IDWT chains.
// Per-j explicit chain so every filter tap is a compile-time immediate.
__global__ __launch_bounds__(1024) void inv_kernel(float* __restrict__ ws) {
    __shared__ float A[4096];
    __shared__ float Bb[2052];
    int q = blockIdx.x;
    int b = q / 5;
    int j = q % 5;

    const float* src;
    int n0;
    switch (j) {
        case 0: src = ws + L4_OFF + b * 262;  n0 = 262;  break;
        case 4: src = ws + H4_OFF + b * 262;  n0 = 262;  break;
        case 3: src = ws + H3_OFF + b * 518;  n0 = 518;  break;
        case 2: src = ws + H2_OFF + b * 1029; n0 = 1029; break;
        default: src = ws + H1_OFF + b * 2051; n0 = 2051; break;
    }
    for (int i = threadIdx.x; i < n0; i += blockDim.x) Bb[i] = src[i];
    __syncthreads();

    float* Sb = ws + S_OFF + (size_t)j * NB * LSEQ + (size_t)b * LSEQ;

    switch (j) {
        case 0:  // 262 ->518 ->1030(1029) ->2052(2051) ->4096, all LO
            inv_step<false>(Bb, 262, A);   __syncthreads();
            inv_step<false>(A, 518, Bb);   __syncthreads();
            inv_step<false>(Bb, 1029, A);  __syncthreads();
            inv_step<false>(A, 2051, Sb);
            break;
        case 4:  // HI then LO x3
            inv_step<true >(Bb, 262, A);   __syncthreads();
            inv_step<false>(A, 518, Bb);   __syncthreads();
            inv_step<false>(Bb, 1029, A);  __syncthreads();
            inv_step<false>(A, 2051, Sb);
            break;
        case 3:  // 518 ->1030(1029) ->2052(2051) ->4096
            inv_step<true >(Bb, 518, A);   __syncthreads();
            inv_step<false>(A, 1029, Bb);  __syncthreads();
            inv_step<false>(Bb, 2051, Sb);
            break;
        case 2:  // 1029 ->2052(2051) ->4096
            inv_step<true >(Bb, 1029, A);  __syncthreads();
            inv_step<false>(A, 2051, Sb);
            break;
        default: // j == 1: 2051 ->4096
            inv_step<true >(Bb, 2051, Sb);
            break;
    }
}

// pe[b,l,c] = sum_j gates[j][c] * S[j][b*L+l]. Pure write-BW kernel.
__global__ __launch_bounds__(256) void expand_kernel(
    const float* __restrict__ ws, float* __restrict__ out) {
    const float* S = ws + S_OFF;
    const float* gates = ws + GATES_OFF;
    __shared__ float gl[5 * DM];
    for (int i = threadIdx.x; i < 5 * DM / 4; i += 256)
        ((float4*)gl)[i] = ((const float4*)gates)[i];
    __syncthreads();

    const size_t BL = (size_t)NB * LSEQ;
    int half = threadIdx.x >> 7;       // 0/1: which row of the pair
    int c4 = threadIdx.x & 127;        // float4 index over 512 channels
    float4 g0 = ((const float4*)(gl + 0 * DM))[c4];
    float4 g1 = ((const float4*)(gl + 1 * DM))[c4];
    float4 g2 = ((const float4*)(gl + 2 * DM))[c4];
    float4 g3 = ((const float4*)(gl + 3 * DM))[c4];
    float4 g4 = ((const float4*)(gl + 4 * DM))[c4];

    int rowBase = blockIdx.x * 32;
#pragma unroll 4
    for (int r = 0; r < 16; ++r) {
        int row = rowBase + r * 2 + half;
        float s0 = S[row];
        float s1 = S[BL + row];
        float s2 = S[2 * BL + row];
        float s3 = S[3 * BL + row];
        float s4 = S[4 * BL + row];
        float4 acc;
        acc.x = fmaf(s4, g4.x, fmaf(s3, g3.x, fmaf(s2, g2.x, fmaf(s1, g1.x, s0 * g0.x))));
        acc.y = fmaf(s4, g4.y, fmaf(s3, g3.y, fmaf(s2, g2.y, fmaf(s1, g1.y, s0 * g0.y))));
        acc.z = fmaf(s4, g4.z, fmaf(s3, g3.z, fmaf(s2, g2.z, fmaf(s1, g1.z, s0 * g0.z))));
        acc.w = fmaf(s4, g4.w, fmaf(s3, g3.w, fmaf(s2, g2.w, fmaf(s1, g1.w, s0 * g0.w))));
        ((float4*)out)[(size_t)row * (DM / 4) + c4] = acc;
    }
}

extern "C" void kernel_launch(void* const* d_in, const int* in_sizes, int n_in,
                              void* d_out, int out_size, void* d_ws, size_t ws_size,
                              hipStream_t stream) {
    const float* x         = (const float*)d_in[0];
    const float* proj_w    = (const float*)d_in[1];
    const float* proj_b    = (const float*)d_in[2];
    const float* scale_emb = (const float*)d_in[3];
    const float* gate_w    = (const float*)d_in[4];
    const float* gate_b    = (const float*)d_in[5];
    float* out = (float*)d_out;
    float* ws  = (float*)d_ws;

    fwd_kernel<<<NB, 1024, 0, stream>>>(x, proj_w, proj_b, ws);
    gates_kernel<<<(DM * 64) / 256, 256, 0, stream>>>(scale_emb, gate_w, gate_b, ws + GATES_OFF);
    inv_kernel<<<NB * 5, 1024, 0, stream>>>(ws);
    expand_kernel<<<(NB * LSEQ) / 32, 256, 0, stream>>>(ws, out);
}

// Round 4
// 105.109 us; speedup vs baseline: 2.3544x; 1.0640x over previous
//
#include <hip/hip_runtime.h>

#define NB   32
#define LSEQ 4096
#define DM   512

// db4 decomposition low-pass; DEC_HI[k] = (-1)^(k+1) * DEC_LO[7-k]
__device__ __constant__ float c_DL[8] = {
    -0.010597401784997278f,  0.032883011666982945f,  0.030841381835986965f,
    -0.18703481171888114f,  -0.02798376941698385f,   0.6308807679295904f,
     0.7148465705525415f,    0.23037781330885523f};
__device__ __constant__ float c_DH[8] = {
    -0.23037781330885523f,   0.7148465705525415f,   -0.6308807679295904f,
    -0.02798376941698385f,   0.18703481171888114f,   0.030841381835986965f,
    -0.032883011666982945f, -0.010597401784997278f};

// workspace layout (floats): gates[5*512] then P[5][NB][2052]
#define GATES_OFF 0
#define P_OFF     (5 * DM)
#define P_STRIDE  2052

__device__ __forceinline__ int reflect_idx(int i, int N) {
    if (i < 0)  i = -1 - i;
    if (i >= N) i = 2 * N - 1 - i;
    return i;
}

// Forward DWT step: symmetric pad (padL=6 at every level) + stride-2 corr.
__device__ void fwd_step(const float* __restrict__ src, int N,
                         float* __restrict__ lo, float* __restrict__ hi) {
    int outsize = (N + 7) >> 1;
    int p = 2 * (outsize - 1) - N + 8;
    int padL = p >> 1;
    for (int t = threadIdx.x; t < outsize; t += blockDim.x) {
        int base = 2 * t - padL;
        float aL = 0.f, aH = 0.f;
#pragma unroll
        for (int k = 0; k < 8; ++k) {
            float xv = src[reflect_idx(base + k, N)];
            aL = fmaf(xv, c_DL[7 - k], aL);
            aH = fmaf(xv, c_DH[7 - k], aH);
        }
        lo[t] = aL;
        hi[t] = aH;
    }
}

// Inverse DWT step: lhs_dilation=2, pad (1,1), VALID corr. Compile-time filter.
// y[t] = sum_{i=0..3} c[(t>>1)+i] * F[2i+1-(t&1)], outN = 2n-6 (all in-range)
template <bool HI>
__device__ void inv_step(const float* __restrict__ c, int n, float* __restrict__ y) {
    int outN = 2 * n - 6;
    for (int t = threadIdx.x; t < outN; t += blockDim.x) {
        int base = t >> 1;
        int odd = t & 1;
        float f0 = odd ? (HI ? c_DH[0] : c_DL[0]) : (HI ? c_DH[1] : c_DL[1]);
        float f1 = odd ? (HI ? c_DH[2] : c_DL[2]) : (HI ? c_DH[3] : c_DL[3]);
        float f2 = odd ? (HI ? c_DH[4] : c_DL[4]) : (HI ? c_DH[5] : c_DL[5]);
        float f3 = odd ? (HI ? c_DH[6] : c_DL[6]) : (HI ? c_DH[7] : c_DL[7]);
        float acc = c[base] * f0;
        acc = fmaf(c[base + 1], f1, acc);
        acc = fmaf(c[base + 2], f2, acc);
        acc = fmaf(c[base + 3], f3, acc);
        y[t] = acc;
    }
}

// Blocks 0..31 (batch b): proj + 4 fwd levels + inverse chains down to the
// 2051-level, 5 chains advancing concurrently, all in LDS. P_j -> ws.
//   P0 = LO(LO(LO(L4)))   P1 = H1 (written during fwd level 1)
//   P2 = HI(H2)           P3 = LO(HI(H3))        P4 = LO(LO(HI(H4)))
// Blocks 32..63: gates (wave-per-channel coalesced GEMV).
__global__ __launch_bounds__(1024) void prep_kernel(
    const float* __restrict__ x, const float* __restrict__ proj_w,
    const float* __restrict__ proj_b, const float* __restrict__ scale_emb,
    const float* __restrict__ gate_w, const float* __restrict__ gate_b,
    float* __restrict__ ws) {
    if (blockIdx.x >= NB) {
        // ---- gates path: 16 waves => 16 channels per block ----
        int lane = threadIdx.x & 63;
        int c = (blockIdx.x - NB) * 16 + (threadIdx.x >> 6);
        const float4* rg = (const float4*)(gate_w + (size_t)c * DM) + lane * 2;
        const float4* rv = (const float4*)(gate_w + (size_t)(c + DM) * DM) + lane * 2;
        float4 a0 = rg[0], a1 = rg[1];
        float4 b0 = rv[0], b1 = rv[1];
        float gacc[5], vacc[5];
#pragma unroll
        for (int j = 0; j < 5; ++j) {
            const float4* sj = (const float4*)(scale_emb + (size_t)j * DM) + lane * 2;
            float4 s0 = sj[0], s1 = sj[1];
            float ga;
            ga = s0.x * a0.x;            ga = fmaf(s0.y, a0.y, ga);
            ga = fmaf(s0.z, a0.z, ga);   ga = fmaf(s0.w, a0.w, ga);
            ga = fmaf(s1.x, a1.x, ga);   ga = fmaf(s1.y, a1.y, ga);
            ga = fmaf(s1.z, a1.z, ga);   ga = fmaf(s1.w, a1.w, ga);
            float va;
            va = s0.x * b0.x;            va = fmaf(s0.y, b0.y, va);
            va = fmaf(s0.z, b0.z, va);   va = fmaf(s0.w, b0.w, va);
            va = fmaf(s1.x, b1.x, va);   va = fmaf(s1.y, b1.y, va);
            va = fmaf(s1.z, b1.z, va);   va = fmaf(s1.w, b1.w, va);
            gacc[j] = ga;
            vacc[j] = va;
        }
#pragma unroll
        for (int j = 0; j < 5; ++j) {
#pragma unroll
            for (int off = 32; off > 0; off >>= 1) {
                gacc[j] += __shfl_xor(gacc[j], off, 64);
                vacc[j] += __shfl_xor(vacc[j], off, 64);
            }
        }
        if (lane == 0) {
            float bg = gate_b[c], bv = gate_b[DM + c];
#pragma unroll
            for (int j = 0; j < 5; ++j) {
                float g = gacc[j] + bg;
                float v = vacc[j] + bv;
                float sg = 1.f / (1.f + expf(-g));
                ws[GATES_OFF + j * DM + c] = sg * tanhf(v);
            }
        }
        return;
    }

    // ---- fwd + inv path ----
    __shared__ float A[4096];
    __shared__ float Bb[2052];
    __shared__ float H2[1029];
    __shared__ float H3[518];
    __shared__ float H4[262];
    __shared__ float L4[262];
    __shared__ float C0a[518],  C4a[518];
    __shared__ float C0b[1030], C4b[1030], C3[1030];

    int b = blockIdx.x;
    float* P = ws + P_OFF;

    float w[8];
#pragma unroll
    for (int k = 0; k < 8; ++k) w[k] = proj_w[k];
    float pb = proj_b[0];

    const float* xb = x + (size_t)b * LSEQ * 8;
    for (int l = threadIdx.x; l < LSEQ; l += blockDim.x) {
        const float4* xv = (const float4*)(xb + (size_t)l * 8);
        float4 a0 = xv[0], a1 = xv[1];
        float acc = pb;
        acc = fmaf(a0.x, w[0], acc); acc = fmaf(a0.y, w[1], acc);
        acc = fmaf(a0.z, w[2], acc); acc = fmaf(a0.w, w[3], acc);
        acc = fmaf(a1.x, w[4], acc); acc = fmaf(a1.y, w[5], acc);
        acc = fmaf(a1.z, w[6], acc); acc = fmaf(a1.w, w[7], acc);
        A[l] = acc;
    }
    __syncthreads();

    // fwd: 4096 -> 2051 -> 1029 -> 518 -> 262. H1 goes straight to P1.
    fwd_step(A, 4096, Bb, P + (size_t)(1 * NB + b) * P_STRIDE);  __syncthreads();
    fwd_step(Bb, 2051, A, H2);  __syncthreads();
    fwd_step(A, 1029, Bb, H3);  __syncthreads();
    fwd_step(Bb, 518, L4, H4);  __syncthreads();

    // inv phase 1: first step of every remaining chain (independent)
    inv_step<false>(L4, 262, C0a);
    inv_step<true >(H4, 262, C4a);
    inv_step<true >(H3, 518, C3);
    inv_step<true >(H2, 1029, P + (size_t)(2 * NB + b) * P_STRIDE);   // P2
    __syncthreads();
    // inv phase 2
    inv_step<false>(C0a, 518, C0b);
    inv_step<false>(C4a, 518, C4b);
    inv_step<false>(C3, 1029, P + (size_t)(3 * NB + b) * P_STRIDE);   // P3
    __syncthreads();
    // inv phase 3
    inv_step<false>(C0b, 1029, P + (size_t)(0 * NB + b) * P_STRIDE);  // P0
    inv_step<false>(C4b, 1029, P + (size_t)(4 * NB + b) * P_STRIDE);  // P4
}

// pe[b,l,c] = sum_j gates[j][c] * s_j[l], with the LAST inverse level inlined:
// s_j[l] = sum_i P_j[b][(l>>1)+i] * F_j[2i+1-(l&1)], F_j = DH if j==1 else DL.
__global__ __launch_bounds__(256) void expand_kernel(
    const float* __restrict__ ws, float* __restrict__ out) {
    const float* gates = ws + GATES_OFF;
    __shared__ float gl[5 * DM];
    __shared__ float sArr[5 * 32];
    for (int i = threadIdx.x; i < 5 * DM / 4; i += 256)
        ((float4*)gl)[i] = ((const float4*)gates)[i];

    int bid = blockIdx.x;
    int b  = bid >> 7;            // 128 blocks per batch
    int l0 = (bid & 127) * 32;

    int t = threadIdx.x;
    if (t < 160) {
        int j = t >> 5, r = t & 31;
        int l = l0 + r;
        int base = l >> 1;
        int odd = l & 1;
        bool hi = (j == 1);
        const float* Pj = ws + P_OFF + (size_t)(j * NB + b) * P_STRIDE;
        float f0 = odd ? (hi ? c_DH[0] : c_DL[0]) : (hi ? c_DH[1] : c_DL[1]);
        float f1 = odd ? (hi ? c_DH[2] : c_DL[2]) : (hi ? c_DH[3] : c_DL[3]);
        float f2 = odd ? (hi ? c_DH[4] : c_DL[4]) : (hi ? c_DH[5] : c_DL[5]);
        float f3 = odd ? (hi ? c_DH[6] : c_DL[6]) : (hi ? c_DH[7] : c_DL[7]);
        float acc = Pj[base] * f0;
        acc = fmaf(Pj[base + 1], f1, acc);
        acc = fmaf(Pj[base + 2], f2, acc);
        acc = fmaf(Pj[base + 3], f3, acc);
        sArr[t] = acc;
    }
    __syncthreads();

    int half = threadIdx.x >> 7;       // 0/1: which row of the pair
    int c4 = threadIdx.x & 127;        // float4 index over 512 channels
    float4 g0 = ((const float4*)(gl + 0 * DM))[c4];
    float4 g1 = ((const float4*)(gl + 1 * DM))[c4];
    float4 g2 = ((const float4*)(gl + 2 * DM))[c4];
    float4 g3 = ((const float4*)(gl + 3 * DM))[c4];
    float4 g4 = ((const float4*)(gl + 4 * DM))[c4];

#pragma unroll 4
    for (int r = 0; r < 16; ++r) {
        int rr = r * 2 + half;
        int row = bid * 32 + rr;
        float s0 = sArr[rr];
        float s1 = sArr[32 + rr];
        float s2 = sArr[64 + rr];
        float s3 = sArr[96 + rr];
        float s4 = sArr[128 + rr];
        float4 acc;
        acc.x = fmaf(s4, g4.x, fmaf(s3, g3.x, fmaf(s2, g2.x, fmaf(s1, g1.x, s0 * g0.x))));
        acc.y = fmaf(s4, g4.y, fmaf(s3, g3.y, fmaf(s2, g2.y, fmaf(s1, g1.y, s0 * g0.y))));
        acc.z = fmaf(s4, g4.z, fmaf(s3, g3.z, fmaf(s2, g2.z, fmaf(s1, g1.z, s0 * g0.z))));
        acc.w = fmaf(s4, g4.w, fmaf(s3, g3.w, fmaf(s2, g2.w, fmaf(s1, g1.w, s0 * g0.w))));
        ((float4*)out)[(size_t)row * (DM / 4) + c4] = acc;
    }
}

extern "C" void kernel_launch(void* const* d_in, const int* in_sizes, int n_in,
                              void* d_out, int out_size, void* d_ws, size_t ws_size,
                              hipStream_t stream) {
    const float* x         = (const float*)d_in[0];
    const float* proj_w    = (const float*)d_in[1];
    const float* proj_b    = (const float*)d_in[2];
    const float* scale_emb = (const float*)d_in[3];
    const float* gate_w    = (const float*)d_in[4];
    const float* gate_b    = (const float*)d_in[5];
    float* out = (float*)d_out;
    float* ws  = (float*)d_ws;

    prep_kernel<<<NB + DM / 16, 1024, 0, stream>>>(x, proj_w, proj_b,
                                                   scale_emb, gate_w, gate_b, ws);
    expand_kernel<<<(NB * LSEQ) / 32, 256, 0, stream>>>(ws, out);
}

// Round 6
// 68.050 us; speedup vs baseline: 3.6366x; 1.5446x over previous
//
#include <hip/hip_runtime.h>

#define NB   32
#define LSEQ 4096
#define DM   512

typedef float f32x4 __attribute__((ext_vector_type(4)));

// db4 decomposition low-pass; DEC_HI[k] = (-1)^(k+1) * DEC_LO[7-k]
__device__ __constant__ float c_DL[8] = {
    -0.010597401784997278f,  0.032883011666982945f,  0.030841381835986965f,
    -0.18703481171888114f,  -0.02798376941698385f,   0.6308807679295904f,
     0.7148465705525415f,    0.23037781330885523f};
__device__ __constant__ float c_DH[8] = {
    -0.23037781330885523f,   0.7148465705525415f,   -0.6308807679295904f,
    -0.02798376941698385f,   0.18703481171888114f,   0.030841381835986965f,
    -0.032883011666982945f, -0.010597401784997278f};

// workspace layout (floats): gates[5*512] then P[5][NB][2052]
#define GATES_OFF 0
#define P_OFF     (5 * DM)
#define P_STRIDE  2052

__device__ __forceinline__ int reflect_idx(int i, int N) {
    if (i < 0)  i = -1 - i;
    if (i >= N) i = 2 * N - 1 - i;
    return i;
}

// Forward DWT step: symmetric pad (padL=6 at every level) + stride-2 corr.
__device__ void fwd_step(const float* __restrict__ src, int N,
                         float* __restrict__ lo, float* __restrict__ hi) {
    int outsize = (N + 7) >> 1;
    int p = 2 * (outsize - 1) - N + 8;
    int padL = p >> 1;
    for (int t = threadIdx.x; t < outsize; t += blockDim.x) {
        int base = 2 * t - padL;
        float aL = 0.f, aH = 0.f;
#pragma unroll
        for (int k = 0; k < 8; ++k) {
            float xv = src[reflect_idx(base + k, N)];
            aL = fmaf(xv, c_DL[7 - k], aL);
            aH = fmaf(xv, c_DH[7 - k], aH);
        }
        lo[t] = aL;
        hi[t] = aH;
    }
}

// Inverse DWT step: lhs_dilation=2, pad (1,1), VALID corr. Compile-time filter.
// y[t] = sum_{i=0..3} c[(t>>1)+i] * F[2i+1-(t&1)], outN = 2n-6 (all in-range)
template <bool HI>
__device__ void inv_step(const float* __restrict__ c, int n, float* __restrict__ y) {
    int outN = 2 * n - 6;
    for (int t = threadIdx.x; t < outN; t += blockDim.x) {
        int base = t >> 1;
        int odd = t & 1;
        float f0 = odd ? (HI ? c_DH[0] : c_DL[0]) : (HI ? c_DH[1] : c_DL[1]);
        float f1 = odd ? (HI ? c_DH[2] : c_DL[2]) : (HI ? c_DH[3] : c_DL[3]);
        float f2 = odd ? (HI ? c_DH[4] : c_DL[4]) : (HI ? c_DH[5] : c_DL[5]);
        float f3 = odd ? (HI ? c_DH[6] : c_DL[6]) : (HI ? c_DH[7] : c_DL[7]);
        float acc = c[base] * f0;
        acc = fmaf(c[base + 1], f1, acc);
        acc = fmaf(c[base + 2], f2, acc);
        acc = fmaf(c[base + 3], f3, acc);
        y[t] = acc;
    }
}

// Blocks 0..31 (batch b): proj + 4 fwd levels + inverse chains down to the
// 2051-level, 5 chains advancing concurrently, all in LDS. P_j -> ws.
//   P0 = LO(LO(LO(L4)))   P1 = H1 (written during fwd level 1)
//   P2 = HI(H2)           P3 = LO(HI(H3))        P4 = LO(LO(HI(H4)))
// Blocks 32..63: gates (wave-per-channel coalesced GEMV).
__global__ __launch_bounds__(1024) void prep_kernel(
    const float* __restrict__ x, const float* __restrict__ proj_w,
    const float* __restrict__ proj_b, const float* __restrict__ scale_emb,
    const float* __restrict__ gate_w, const float* __restrict__ gate_b,
    float* __restrict__ ws) {
    if (blockIdx.x >= NB) {
        // ---- gates path: 16 waves => 16 channels per block ----
        int lane = threadIdx.x & 63;
        int c = (blockIdx.x - NB) * 16 + (threadIdx.x >> 6);
        const float4* rg = (const float4*)(gate_w + (size_t)c * DM) + lane * 2;
        const float4* rv = (const float4*)(gate_w + (size_t)(c + DM) * DM) + lane * 2;
        float4 a0 = rg[0], a1 = rg[1];
        float4 b0 = rv[0], b1 = rv[1];
        float gacc[5], vacc[5];
#pragma unroll
        for (int j = 0; j < 5; ++j) {
            const float4* sj = (const float4*)(scale_emb + (size_t)j * DM) + lane * 2;
            float4 s0 = sj[0], s1 = sj[1];
            float ga;
            ga = s0.x * a0.x;            ga = fmaf(s0.y, a0.y, ga);
            ga = fmaf(s0.z, a0.z, ga);   ga = fmaf(s0.w, a0.w, ga);
            ga = fmaf(s1.x, a1.x, ga);   ga = fmaf(s1.y, a1.y, ga);
            ga = fmaf(s1.z, a1.z, ga);   ga = fmaf(s1.w, a1.w, ga);
            float va;
            va = s0.x * b0.x;            va = fmaf(s0.y, b0.y, va);
            va = fmaf(s0.z, b0.z, va);   va = fmaf(s0.w, b0.w, va);
            va = fmaf(s1.x, b1.x, va);   va = fmaf(s1.y, b1.y, va);
            va = fmaf(s1.z, b1.z, va);   va = fmaf(s1.w, b1.w, va);
            gacc[j] = ga;
            vacc[j] = va;
        }
#pragma unroll
        for (int j = 0; j < 5; ++j) {
#pragma unroll
            for (int off = 32; off > 0; off >>= 1) {
                gacc[j] += __shfl_xor(gacc[j], off, 64);
                vacc[j] += __shfl_xor(vacc[j], off, 64);
            }
        }
        if (lane == 0) {
            float bg = gate_b[c], bv = gate_b[DM + c];
#pragma unroll
            for (int j = 0; j < 5; ++j) {
                float g = gacc[j] + bg;
                float v = vacc[j] + bv;
                float sg = 1.f / (1.f + expf(-g));
                ws[GATES_OFF + j * DM + c] = sg * tanhf(v);
            }
        }
        return;
    }

    // ---- fwd + inv path ----
    __shared__ float A[4096];
    __shared__ float Bb[2052];
    __shared__ float H2[1029];
    __shared__ float H3[518];
    __shared__ float H4[262];
    __shared__ float L4[262];
    __shared__ float C0a[518],  C4a[518];
    __shared__ float C0b[1030], C4b[1030], C3[1030];

    int b = blockIdx.x;
    float* P = ws + P_OFF;

    float w[8];
#pragma unroll
    for (int k = 0; k < 8; ++k) w[k] = proj_w[k];
    float pb = proj_b[0];

    const float* xb = x + (size_t)b * LSEQ * 8;
    for (int l = threadIdx.x; l < LSEQ; l += blockDim.x) {
        const float4* xv = (const float4*)(xb + (size_t)l * 8);
        float4 a0 = xv[0], a1 = xv[1];
        float acc = pb;
        acc = fmaf(a0.x, w[0], acc); acc = fmaf(a0.y, w[1], acc);
        acc = fmaf(a0.z, w[2], acc); acc = fmaf(a0.w, w[3], acc);
        acc = fmaf(a1.x, w[4], acc); acc = fmaf(a1.y, w[5], acc);
        acc = fmaf(a1.z, w[6], acc); acc = fmaf(a1.w, w[7], acc);
        A[l] = acc;
    }
    __syncthreads();

    // fwd: 4096 -> 2051 -> 1029 -> 518 -> 262. H1 goes straight to P1.
    fwd_step(A, 4096, Bb, P + (size_t)(1 * NB + b) * P_STRIDE);  __syncthreads();
    fwd_step(Bb, 2051, A, H2);  __syncthreads();
    fwd_step(A, 1029, Bb, H3);  __syncthreads();
    fwd_step(Bb, 518, L4, H4);  __syncthreads();

    // inv phase 1: first step of every remaining chain (independent)
    inv_step<false>(L4, 262, C0a);
    inv_step<true >(H4, 262, C4a);
    inv_step<true >(H3, 518, C3);
    inv_step<true >(H2, 1029, P + (size_t)(2 * NB + b) * P_STRIDE);   // P2
    __syncthreads();
    // inv phase 2
    inv_step<false>(C0a, 518, C0b);
    inv_step<false>(C4a, 518, C4b);
    inv_step<false>(C3, 1029, P + (size_t)(3 * NB + b) * P_STRIDE);   // P3
    __syncthreads();
    // inv phase 3
    inv_step<false>(C0b, 1029, P + (size_t)(0 * NB + b) * P_STRIDE);  // P0
    inv_step<false>(C4b, 1029, P + (size_t)(4 * NB + b) * P_STRIDE);  // P4
}

// pe[b,l,c] = sum_j gates[j][c] * s_j[l], with the LAST inverse level inlined:
// s_j[l] = sum_i P_j[b][(l>>1)+i] * F_j[2i+1-(l&1)], F_j = DH if j==1 else DL.
// Output stores are nontemporal: written once, never re-read.
__global__ __launch_bounds__(256) void expand_kernel(
    const float* __restrict__ ws, float* __restrict__ out) {
    const float* gates = ws + GATES_OFF;
    __shared__ float gl[5 * DM];
    __shared__ float sArr[5 * 32];
    for (int i = threadIdx.x; i < 5 * DM / 4; i += 256)
        ((float4*)gl)[i] = ((const float4*)gates)[i];

    int bid = blockIdx.x;
    int b  = bid >> 7;            // 128 blocks per batch
    int l0 = (bid & 127) * 32;

    int t = threadIdx.x;
    if (t < 160) {
        int j = t >> 5, r = t & 31;
        int l = l0 + r;
        int base = l >> 1;
        int odd = l & 1;
        bool hi = (j == 1);
        const float* Pj = ws + P_OFF + (size_t)(j * NB + b) * P_STRIDE;
        float f0 = odd ? (hi ? c_DH[0] : c_DL[0]) : (hi ? c_DH[1] : c_DL[1]);
        float f1 = odd ? (hi ? c_DH[2] : c_DL[2]) : (hi ? c_DH[3] : c_DL[3]);
        float f2 = odd ? (hi ? c_DH[4] : c_DL[4]) : (hi ? c_DH[5] : c_DL[5]);
        float f3 = odd ? (hi ? c_DH[6] : c_DL[6]) : (hi ? c_DH[7] : c_DL[7]);
        float acc = Pj[base] * f0;
        acc = fmaf(Pj[base + 1], f1, acc);
        acc = fmaf(Pj[base + 2], f2, acc);
        acc = fmaf(Pj[base + 3], f3, acc);
        sArr[t] = acc;
    }
    __syncthreads();

    int half = threadIdx.x >> 7;       // 0/1: which row of the pair
    int c4 = threadIdx.x & 127;        // float4 index over 512 channels
    float4 g0 = ((const float4*)(gl + 0 * DM))[c4];
    float4 g1 = ((const float4*)(gl + 1 * DM))[c4];
    float4 g2 = ((const float4*)(gl + 2 * DM))[c4];
    float4 g3 = ((const float4*)(gl + 3 * DM))[c4];
    float4 g4 = ((const float4*)(gl + 4 * DM))[c4];

#pragma unroll 4
    for (int r = 0; r < 16; ++r) {
        int rr = r * 2 + half;
        int row = bid * 32 + rr;
        float s0 = sArr[rr];
        float s1 = sArr[32 + rr];
        float s2 = sArr[64 + rr];
        float s3 = sArr[96 + rr];
        float s4 = sArr[128 + rr];
        f32x4 acc;
        acc.x = fmaf(s4, g4.x, fmaf(s3, g3.x, fmaf(s2, g2.x, fmaf(s1, g1.x, s0 * g0.x))));
        acc.y = fmaf(s4, g4.y, fmaf(s3, g3.y, fmaf(s2, g2.y, fmaf(s1, g1.y, s0 * g0.y))));
        acc.z = fmaf(s4, g4.z, fmaf(s3, g3.z, fmaf(s2, g2.z, fmaf(s1, g1.z, s0 * g0.z))));
        acc.w = fmaf(s4, g4.w, fmaf(s3, g3.w, fmaf(s2, g2.w, fmaf(s1, g1.w, s0 * g0.w))));
        __builtin_nontemporal_store(acc, (f32x4*)out + (size_t)row * (DM / 4) + c4);
    }
}

extern "C" void kernel_launch(void* const* d_in, const int* in_sizes, int n_in,
                              void* d_out, int out_size, void* d_ws, size_t ws_size,
                              hipStream_t stream) {
    const float* x         = (const float*)d_in[0];
    const float* proj_w    = (const float*)d_in[1];
    const float* proj_b    = (const float*)d_in[2];
    const float* scale_emb = (const float*)d_in[3];
    const float* gate_w    = (const float*)d_in[4];
    const float* gate_b    = (const float*)d_in[5];
    float* out = (float*)d_out;
    float* ws  = (float*)d_ws;

    prep_kernel<<<NB + DM / 16, 1024, 0, stream>>>(x, proj_w, proj_b,
                                                   scale_emb, gate_w, gate_b, ws);
    expand_kernel<<<(NB * LSEQ) / 32, 256, 0, stream>>>(ws, out);
}

// Round 7
// 66.302 us; speedup vs baseline: 3.7325x; 1.0264x over previous
//
#include <hip/hip_runtime.h>

#define NB    32
#define LSEQ  4096
#define DM    512
#define ROWS  64
#define CHUNKS (LSEQ / ROWS)   // 64 blocks per batch

typedef float f32x4 __attribute__((ext_vector_type(4)));

// db4 decomposition low-pass; DEC_HI[k] = (-1)^(k+1) * DEC_LO[7-k]
__device__ __constant__ float c_DL[8] = {
    -0.010597401784997278f,  0.032883011666982945f,  0.030841381835986965f,
    -0.18703481171888114f,  -0.02798376941698385f,   0.6308807679295904f,
     0.7148465705525415f,    0.23037781330885523f};
__device__ __constant__ float c_DH[8] = {
    -0.23037781330885523f,   0.7148465705525415f,   -0.6308807679295904f,
    -0.02798376941698385f,   0.18703481171888114f,   0.030841381835986965f,
    -0.032883011666982945f, -0.010597401784997278f};

__device__ __forceinline__ int imin(int a, int b) { return a < b ? a : b; }
__device__ __forceinline__ int imax(int a, int b) { return a > b ? a : b; }

__device__ __forceinline__ int reflect_idx(int i, int N) {
    if (i < 0)  i = -1 - i;
    if (i >= N) i = 2 * N - 1 - i;
    return i;
}

// Forward DWT (one filter) over output window [d_lo, d_hi]; src is a window
// array covering all (reflected) reads. y[t] = sum_k src[ref(2t-6+k)]*F[7-k].
template <bool HI>
__device__ void fwd_range(const float* __restrict__ src, int src_lo, int Nsrc,
                          float* __restrict__ dst, int d_lo, int d_hi) {
    for (int t = d_lo + (int)threadIdx.x; t <= d_hi; t += 256) {
        int base = 2 * t - 6;
        float acc = 0.f;
#pragma unroll
        for (int k = 0; k < 8; ++k) {
            float xv = src[reflect_idx(base + k, Nsrc) - src_lo];
            acc = fmaf(xv, HI ? c_DH[7 - k] : c_DL[7 - k], acc);
        }
        dst[t - d_lo] = acc;
    }
}

// Inverse DWT step over output window [y_lo, y_hi]; c is a window array.
// y[t] = sum_{i=0..3} c[(t>>1)+i] * F[2i+1-(t&1)]  (always in-range).
template <bool HI>
__device__ void inv_range(const float* __restrict__ c, int c_lo,
                          float* __restrict__ y, int y_lo, int y_hi) {
    for (int t = y_lo + (int)threadIdx.x; t <= y_hi; t += 256) {
        int base = (t >> 1) - c_lo;
        int odd = t & 1;
        float f0 = odd ? (HI ? c_DH[0] : c_DL[0]) : (HI ? c_DH[1] : c_DL[1]);
        float f1 = odd ? (HI ? c_DH[2] : c_DL[2]) : (HI ? c_DH[3] : c_DL[3]);
        float f2 = odd ? (HI ? c_DH[4] : c_DL[4]) : (HI ? c_DH[5] : c_DL[5]);
        float f3 = odd ? (HI ? c_DH[6] : c_DL[6]) : (HI ? c_DH[7] : c_DL[7]);
        float acc = c[base] * f0;
        acc = fmaf(c[base + 1], f1, acc);
        acc = fmaf(c[base + 2], f2, acc);
        acc = fmaf(c[base + 3], f3, acc);
        y[t - y_lo] = acc;
    }
}

// One wave per channel c: coalesced rows gw[c], gw[c+512]; 5 g/v dots;
// shuffle-reduce; lane 0 writes gates[j][c] = sigmoid(g)*tanh(v).
__global__ __launch_bounds__(1024) void gates_kernel(
    const float* __restrict__ scale_emb, const float* __restrict__ gate_w,
    const float* __restrict__ gate_b, float* __restrict__ gates) {
    int lane = threadIdx.x & 63;
    int c = blockIdx.x * 16 + (threadIdx.x >> 6);
    const float4* rg = (const float4*)(gate_w + (size_t)c * DM) + lane * 2;
    const float4* rv = (const float4*)(gate_w + (size_t)(c + DM) * DM) + lane * 2;
    float4 a0 = rg[0], a1 = rg[1];
    float4 b0 = rv[0], b1 = rv[1];
    float gacc[5], vacc[5];
#pragma unroll
    for (int j = 0; j < 5; ++j) {
        const float4* sj = (const float4*)(scale_emb + (size_t)j * DM) + lane * 2;
        float4 s0 = sj[0], s1 = sj[1];
        float ga;
        ga = s0.x * a0.x;            ga = fmaf(s0.y, a0.y, ga);
        ga = fmaf(s0.z, a0.z, ga);   ga = fmaf(s0.w, a0.w, ga);
        ga = fmaf(s1.x, a1.x, ga);   ga = fmaf(s1.y, a1.y, ga);
        ga = fmaf(s1.z, a1.z, ga);   ga = fmaf(s1.w, a1.w, ga);
        float va;
        va = s0.x * b0.x;            va = fmaf(s0.y, b0.y, va);
        va = fmaf(s0.z, b0.z, va);   va = fmaf(s0.w, b0.w, va);
        va = fmaf(s1.x, b1.x, va);   va = fmaf(s1.y, b1.y, va);
        va = fmaf(s1.z, b1.z, va);   va = fmaf(s1.w, b1.w, va);
        gacc[j] = ga;
        vacc[j] = va;
    }
#pragma unroll
    for (int j = 0; j < 5; ++j) {
#pragma unroll
        for (int off = 32; off > 0; off >>= 1) {
            gacc[j] += __shfl_xor(gacc[j], off, 64);
            vacc[j] += __shfl_xor(vacc[j], off, 64);
        }
    }
    if (lane == 0) {
        float bg = gate_b[c], bv = gate_b[DM + c];
#pragma unroll
        for (int j = 0; j < 5; ++j) {
            float g = gacc[j] + bg;
            float v = vacc[j] + bv;
            float sg = 1.f / (1.f + expf(-g));
            gates[j * DM + c] = sg * tanhf(v);
        }
    }
}

// Fused cone kernel: each block owns 64 output rows of one batch.
// It recomputes its dependency cone (proj -> 4 fwd levels -> inverse chains
// -> final inverse level) entirely in LDS, then does the rank-5 expansion
// with nontemporal float4 stores. Per-element math identical to reference.
__global__ __launch_bounds__(256) void fused_kernel(
    const float* __restrict__ x, const float* __restrict__ proj_w,
    const float* __restrict__ proj_b, const float* __restrict__ gates,
    float* __restrict__ out) {
    __shared__ float GL[5 * DM];
    __shared__ float XW[288];
    __shared__ float LO1[140], LO2[68], LO3[32];
    __shared__ float HI1[36], H2W[24], H3W[16], L4W[12], H4W[12];
    __shared__ float AW[16], A4W[16], A3W[24], BW[24], B4W[24];
    __shared__ float P0W[36], P2W[36], P3W[36], P4W[36];
    __shared__ float SJ[5 * ROWS];

    int bid = blockIdx.x;
    int b  = bid >> 6;               // batch (CHUNKS = 64)
    int l0 = (bid & 63) * ROWS;      // in-batch first output row

    // ---- dependency-cone windows (uniform scalar math) ----
    int p0 = l0 >> 1,  p1 = ((l0 + ROWS - 1) >> 1) + 3;   // P level (2051)
    int b0 = p0 >> 1,  b1 = (p1 >> 1) + 3;                // 1029 level
    int a0 = b0 >> 1,  a1 = (b1 >> 1) + 3;                // 518 level
    int w0 = a0 >> 1,  w1 = (a1 >> 1) + 3;                // 262 level
    // lo3 window: needs of L4/H4, union H3's domain W_A
    int t3lo = imax(imin(imin(2 * w0 - 6, a0), 517), 0);
    int t3hi = imin(imax(imax(2 * w1 + 1, a1), 0), 517);
    // lo2 window: needs of lo3 and H3(W_A)
    int t2lo = imax(imin(2 * t3lo - 6, 2 * a0 - 6), 0);
    int t2hi = imin(imax(2 * t3hi + 1, 2 * a1 + 1), 1028);
    // lo1 window: needs of lo2 and H2(W_B)
    int t1lo = imax(imin(2 * t2lo - 6, 2 * b0 - 6), 0);
    int t1hi = imin(imax(2 * t2hi + 1, 2 * b1 + 1), 2050);
    // x window: needs of lo1 and hi1(W_P)
    int txlo = imax(imin(2 * t1lo - 6, 2 * p0 - 6), 0);
    int txhi = imin(imax(2 * t1hi + 1, 2 * p1 + 1), 4095);

    // ---- stage 1: gates -> LDS, projection over x window ----
    for (int i = threadIdx.x; i < 5 * DM / 4; i += 256)
        ((f32x4*)GL)[i] = ((const f32x4*)gates)[i];
    float w[8];
#pragma unroll
    for (int k = 0; k < 8; ++k) w[k] = proj_w[k];
    float pb = proj_b[0];
    const float* xb = x + (size_t)b * LSEQ * 8;
    for (int i = txlo + (int)threadIdx.x; i <= txhi; i += 256) {
        const float4* xv = (const float4*)(xb + (size_t)i * 8);
        float4 q0 = xv[0], q1 = xv[1];
        float acc = pb;
        acc = fmaf(q0.x, w[0], acc); acc = fmaf(q0.y, w[1], acc);
        acc = fmaf(q0.z, w[2], acc); acc = fmaf(q0.w, w[3], acc);
        acc = fmaf(q1.x, w[4], acc); acc = fmaf(q1.y, w[5], acc);
        acc = fmaf(q1.z, w[6], acc); acc = fmaf(q1.w, w[7], acc);
        XW[i - txlo] = acc;
    }
    __syncthreads();

    // ---- forward levels ----
    fwd_range<false>(XW, txlo, 4096, LO1, t1lo, t1hi);
    fwd_range<true >(XW, txlo, 4096, HI1, p0, p1);        // P1 = h1
    __syncthreads();
    fwd_range<false>(LO1, t1lo, 2051, LO2, t2lo, t2hi);
    fwd_range<true >(LO1, t1lo, 2051, H2W, b0, b1);
    __syncthreads();
    fwd_range<false>(LO2, t2lo, 1029, LO3, t3lo, t3hi);
    fwd_range<true >(LO2, t2lo, 1029, H3W, a0, a1);
    __syncthreads();
    fwd_range<false>(LO3, t3lo, 518, L4W, w0, w1);
    fwd_range<true >(LO3, t3lo, 518, H4W, w0, w1);
    __syncthreads();

    // ---- inverse chains (to the 2051-equivalent level) ----
    inv_range<false>(L4W, w0, AW,  a0, a1);               // chain0: LO(L4)
    inv_range<true >(H4W, w0, A4W, a0, a1);               // chain4: HI(H4)
    inv_range<true >(H3W, a0, A3W, b0, b1);               // chain3: HI(H3)
    inv_range<true >(H2W, b0, P2W, p0, p1);               // P2 = HI(H2)
    __syncthreads();
    inv_range<false>(AW,  a0, BW,  b0, b1);
    inv_range<false>(A4W, a0, B4W, b0, b1);
    inv_range<false>(A3W, b0, P3W, p0, p1);               // P3
    __syncthreads();
    inv_range<false>(BW,  b0, P0W, p0, p1);               // P0
    inv_range<false>(B4W, b0, P4W, p0, p1);               // P4
    __syncthreads();

    // ---- final inverse level: s_j on the block's 64 rows ----
    for (int idx = threadIdx.x; idx < 5 * ROWS; idx += 256) {
        int j = idx >> 6;
        int r = idx & (ROWS - 1);
        int l = l0 + r;
        int base = (l >> 1) - p0;
        int odd = l & 1;
        const float* Pj = (j == 0) ? P0W : (j == 1) ? HI1 :
                          (j == 2) ? P2W : (j == 3) ? P3W : P4W;
        bool hi = (j == 1);
        float f0 = odd ? (hi ? c_DH[0] : c_DL[0]) : (hi ? c_DH[1] : c_DL[1]);
        float f1 = odd ? (hi ? c_DH[2] : c_DL[2]) : (hi ? c_DH[3] : c_DL[3]);
        float f2 = odd ? (hi ? c_DH[4] : c_DL[4]) : (hi ? c_DH[5] : c_DL[5]);
        float f3 = odd ? (hi ? c_DH[6] : c_DL[6]) : (hi ? c_DH[7] : c_DL[7]);
        float acc = Pj[base] * f0;
        acc = fmaf(Pj[base + 1], f1, acc);
        acc = fmaf(Pj[base + 2], f2, acc);
        acc = fmaf(Pj[base + 3], f3, acc);
        SJ[idx] = acc;
    }
    __syncthreads();

    // ---- rank-5 expansion, nontemporal stores ----
    int half = threadIdx.x >> 7;       // which row of each pair
    int c4 = threadIdx.x & 127;        // float4 index over 512 channels
    f32x4 g0 = ((const f32x4*)(GL + 0 * DM))[c4];
    f32x4 g1 = ((const f32x4*)(GL + 1 * DM))[c4];
    f32x4 g2 = ((const f32x4*)(GL + 2 * DM))[c4];
    f32x4 g3 = ((const f32x4*)(GL + 3 * DM))[c4];
    f32x4 g4 = ((const f32x4*)(GL + 4 * DM))[c4];

    size_t rowbase = (size_t)b * LSEQ + l0;
#pragma unroll 4
    for (int r = 0; r < ROWS / 2; ++r) {
        int rr = r * 2 + half;
        float s0 = SJ[rr];
        float s1 = SJ[64 + rr];
        float s2 = SJ[128 + rr];
        float s3 = SJ[192 + rr];
        float s4 = SJ[256 + rr];
        f32x4 acc;
        acc.x = fmaf(s4, g4.x, fmaf(s3, g3.x, fmaf(s2, g2.x, fmaf(s1, g1.x, s0 * g0.x))));
        acc.y = fmaf(s4, g4.y, fmaf(s3, g3.y, fmaf(s2, g2.y, fmaf(s1, g1.y, s0 * g0.y))));
        acc.z = fmaf(s4, g4.z, fmaf(s3, g3.z, fmaf(s2, g2.z, fmaf(s1, g1.z, s0 * g0.z))));
        acc.w = fmaf(s4, g4.w, fmaf(s3, g3.w, fmaf(s2, g2.w, fmaf(s1, g1.w, s0 * g0.w))));
        __builtin_nontemporal_store(acc, (f32x4*)out + (rowbase + rr) * (DM / 4) + c4);
    }
}

extern "C" void kernel_launch(void* const* d_in, const int* in_sizes, int n_in,
                              void* d_out, int out_size, void* d_ws, size_t ws_size,
                              hipStream_t stream) {
    const float* x         = (const float*)d_in[0];
    const float* proj_w    = (const float*)d_in[1];
    const float* proj_b    = (const float*)d_in[2];
    const float* scale_emb = (const float*)d_in[3];
    const float* gate_w    = (const float*)d_in[4];
    const float* gate_b    = (const float*)d_in[5];
    float* out   = (float*)d_out;
    float* gates = (float*)d_ws;     // 5*512 floats

    gates_kernel<<<32, 1024, 0, stream>>>(scale_emb, gate_w, gate_b, gates);
    fused_kernel<<<NB * CHUNKS, 256, 0, stream>>>(x, proj_w, proj_b, gates, out);
}

// Round 8
// 64.896 us; speedup vs baseline: 3.8133x; 1.0217x over previous
//
#include <hip/hip_runtime.h>

#define NB    32
#define LSEQ  4096
#define DM    512
#define ROWS  64
#define CHUNKS (LSEQ / ROWS)   // 64 blocks per batch

typedef float f32x4 __attribute__((ext_vector_type(4)));

// db4 decomposition low-pass; DEC_HI[k] = (-1)^(k+1) * DEC_LO[7-k]
__device__ __constant__ float c_DL[8] = {
    -0.010597401784997278f,  0.032883011666982945f,  0.030841381835986965f,
    -0.18703481171888114f,  -0.02798376941698385f,   0.6308807679295904f,
     0.7148465705525415f,    0.23037781330885523f};
__device__ __constant__ float c_DH[8] = {
    -0.23037781330885523f,   0.7148465705525415f,   -0.6308807679295904f,
    -0.02798376941698385f,   0.18703481171888114f,   0.030841381835986965f,
    -0.032883011666982945f, -0.010597401784997278f};

__device__ __forceinline__ int imin(int a, int b) { return a < b ? a : b; }
__device__ __forceinline__ int imax(int a, int b) { return a > b ? a : b; }

__device__ __forceinline__ int reflect_idx(int i, int N) {
    if (i < 0)  i = -1 - i;
    if (i >= N) i = 2 * N - 1 - i;
    return i;
}

// Forward DWT (one filter) over output window [d_lo, d_hi]; src is a window
// array covering all (reflected) reads. y[t] = sum_k src[ref(2t-6+k)]*F[7-k].
template <bool HI>
__device__ void fwd_range(const float* __restrict__ src, int src_lo, int Nsrc,
                          float* __restrict__ dst, int d_lo, int d_hi) {
    for (int t = d_lo + (int)threadIdx.x; t <= d_hi; t += 256) {
        int base = 2 * t - 6;
        float acc = 0.f;
#pragma unroll
        for (int k = 0; k < 8; ++k) {
            float xv = src[reflect_idx(base + k, Nsrc) - src_lo];
            acc = fmaf(xv, HI ? c_DH[7 - k] : c_DL[7 - k], acc);
        }
        dst[t - d_lo] = acc;
    }
}

// Inverse DWT step over output window [y_lo, y_hi]; c is a window array.
// y[t] = sum_{i=0..3} c[(t>>1)+i] * F[2i+1-(t&1)]  (always in-range).
template <bool HI>
__device__ void inv_range(const float* __restrict__ c, int c_lo,
                          float* __restrict__ y, int y_lo, int y_hi) {
    for (int t = y_lo + (int)threadIdx.x; t <= y_hi; t += 256) {
        int base = (t >> 1) - c_lo;
        int odd = t & 1;
        float f0 = odd ? (HI ? c_DH[0] : c_DL[0]) : (HI ? c_DH[1] : c_DL[1]);
        float f1 = odd ? (HI ? c_DH[2] : c_DL[2]) : (HI ? c_DH[3] : c_DL[3]);
        float f2 = odd ? (HI ? c_DH[4] : c_DL[4]) : (HI ? c_DH[5] : c_DL[5]);
        float f3 = odd ? (HI ? c_DH[6] : c_DL[6]) : (HI ? c_DH[7] : c_DL[7]);
        float acc = c[base] * f0;
        acc = fmaf(c[base + 1], f1, acc);
        acc = fmaf(c[base + 2], f2, acc);
        acc = fmaf(c[base + 3], f3, acc);
        y[t - y_lo] = acc;
    }
}

// One wave per channel c: coalesced rows gw[c], gw[c+512]; 5 g/v dots;
// shuffle-reduce; lane 0 writes gates[j][c] = sigmoid(g)*tanh(v).
__global__ __launch_bounds__(1024) void gates_kernel(
    const float* __restrict__ scale_emb, const float* __restrict__ gate_w,
    const float* __restrict__ gate_b, float* __restrict__ gates) {
    int lane = threadIdx.x & 63;
    int c = blockIdx.x * 16 + (threadIdx.x >> 6);
    const float4* rg = (const float4*)(gate_w + (size_t)c * DM) + lane * 2;
    const float4* rv = (const float4*)(gate_w + (size_t)(c + DM) * DM) + lane * 2;
    float4 a0 = rg[0], a1 = rg[1];
    float4 b0 = rv[0], b1 = rv[1];
    float gacc[5], vacc[5];
#pragma unroll
    for (int j = 0; j < 5; ++j) {
        const float4* sj = (const float4*)(scale_emb + (size_t)j * DM) + lane * 2;
        float4 s0 = sj[0], s1 = sj[1];
        float ga;
        ga = s0.x * a0.x;            ga = fmaf(s0.y, a0.y, ga);
        ga = fmaf(s0.z, a0.z, ga);   ga = fmaf(s0.w, a0.w, ga);
        ga = fmaf(s1.x, a1.x, ga);   ga = fmaf(s1.y, a1.y, ga);
        ga = fmaf(s1.z, a1.z, ga);   ga = fmaf(s1.w, a1.w, ga);
        float va;
        va = s0.x * b0.x;            va = fmaf(s0.y, b0.y, va);
        va = fmaf(s0.z, b0.z, va);   va = fmaf(s0.w, b0.w, va);
        va = fmaf(s1.x, b1.x, va);   va = fmaf(s1.y, b1.y, va);
        va = fmaf(s1.z, b1.z, va);   va = fmaf(s1.w, b1.w, va);
        gacc[j] = ga;
        vacc[j] = va;
    }
#pragma unroll
    for (int j = 0; j < 5; ++j) {
#pragma unroll
        for (int off = 32; off > 0; off >>= 1) {
            gacc[j] += __shfl_xor(gacc[j], off, 64);
            vacc[j] += __shfl_xor(vacc[j], off, 64);
        }
    }
    if (lane == 0) {
        float bg = gate_b[c], bv = gate_b[DM + c];
#pragma unroll
        for (int j = 0; j < 5; ++j) {
            float g = gacc[j] + bg;
            float v = vacc[j] + bv;
            float sg = 1.f / (1.f + expf(-g));
            gates[j * DM + c] = sg * tanhf(v);
        }
    }
}

// Fused cone kernel: each block owns 64 output rows of one batch.
// __launch_bounds__(256, 8): cap VGPR at 64 so all 2048 blocks are resident
// (8 blocks/CU x 256 CUs) -> the cone phase runs exactly once, at kernel
// start, and the rest is a pure nontemporal store stream.
__global__ __launch_bounds__(256, 8) void fused_kernel(
    const float* __restrict__ x, const float* __restrict__ proj_w,
    const float* __restrict__ proj_b, const float* __restrict__ gates,
    float* __restrict__ out) {
    __shared__ float GL[5 * DM];
    __shared__ float XW[288];
    __shared__ float LO1[140], LO2[68], LO3[32];
    __shared__ float HI1[36], H2W[24], H3W[16], L4W[12], H4W[12];
    __shared__ float AW[16], A4W[16], A3W[24], BW[24], B4W[24];
    __shared__ float P0W[36], P2W[36], P3W[36], P4W[36];
    __shared__ float SJ[5 * ROWS];

    int bid = blockIdx.x;
    int b  = bid >> 6;               // batch (CHUNKS = 64)
    int l0 = (bid & 63) * ROWS;      // in-batch first output row

    // ---- dependency-cone windows (uniform scalar math) ----
    int p0 = l0 >> 1,  p1 = ((l0 + ROWS - 1) >> 1) + 3;   // P level (2051)
    int b0 = p0 >> 1,  b1 = (p1 >> 1) + 3;                // 1029 level
    int a0 = b0 >> 1,  a1 = (b1 >> 1) + 3;                // 518 level
    int w0 = a0 >> 1,  w1 = (a1 >> 1) + 3;                // 262 level
    // lo3 window: needs of L4/H4, union H3's domain W_A
    int t3lo = imax(imin(imin(2 * w0 - 6, a0), 517), 0);
    int t3hi = imin(imax(imax(2 * w1 + 1, a1), 0), 517);
    // lo2 window: needs of lo3 and H3(W_A)
    int t2lo = imax(imin(2 * t3lo - 6, 2 * a0 - 6), 0);
    int t2hi = imin(imax(2 * t3hi + 1, 2 * a1 + 1), 1028);
    // lo1 window: needs of lo2 and H2(W_B)
    int t1lo = imax(imin(2 * t2lo - 6, 2 * b0 - 6), 0);
    int t1hi = imin(imax(2 * t2hi + 1, 2 * b1 + 1), 2050);
    // x window: needs of lo1 and hi1(W_P)
    int txlo = imax(imin(2 * t1lo - 6, 2 * p0 - 6), 0);
    int txhi = imin(imax(2 * t1hi + 1, 2 * p1 + 1), 4095);

    // ---- stage 1: gates -> LDS, projection over x window ----
    for (int i = threadIdx.x; i < 5 * DM / 4; i += 256)
        ((f32x4*)GL)[i] = ((const f32x4*)gates)[i];
    float w[8];
#pragma unroll
    for (int k = 0; k < 8; ++k) w[k] = proj_w[k];
    float pb = proj_b[0];
    const float* xb = x + (size_t)b * LSEQ * 8;
    for (int i = txlo + (int)threadIdx.x; i <= txhi; i += 256) {
        const float4* xv = (const float4*)(xb + (size_t)i * 8);
        float4 q0 = xv[0], q1 = xv[1];
        float acc = pb;
        acc = fmaf(q0.x, w[0], acc); acc = fmaf(q0.y, w[1], acc);
        acc = fmaf(q0.z, w[2], acc); acc = fmaf(q0.w, w[3], acc);
        acc = fmaf(q1.x, w[4], acc); acc = fmaf(q1.y, w[5], acc);
        acc = fmaf(q1.z, w[6], acc); acc = fmaf(q1.w, w[7], acc);
        XW[i - txlo] = acc;
    }
    __syncthreads();

    // ---- forward levels ----
    fwd_range<false>(XW, txlo, 4096, LO1, t1lo, t1hi);
    fwd_range<true >(XW, txlo, 4096, HI1, p0, p1);        // P1 = h1
    __syncthreads();
    fwd_range<false>(LO1, t1lo, 2051, LO2, t2lo, t2hi);
    fwd_range<true >(LO1, t1lo, 2051, H2W, b0, b1);
    __syncthreads();
    fwd_range<false>(LO2, t2lo, 1029, LO3, t3lo, t3hi);
    fwd_range<true >(LO2, t2lo, 1029, H3W, a0, a1);
    __syncthreads();
    fwd_range<false>(LO3, t3lo, 518, L4W, w0, w1);
    fwd_range<true >(LO3, t3lo, 518, H4W, w0, w1);
    __syncthreads();

    // ---- inverse chains (to the 2051-equivalent level) ----
    inv_range<false>(L4W, w0, AW,  a0, a1);               // chain0: LO(L4)
    inv_range<true >(H4W, w0, A4W, a0, a1);               // chain4: HI(H4)
    inv_range<true >(H3W, a0, A3W, b0, b1);               // chain3: HI(H3)
    inv_range<true >(H2W, b0, P2W, p0, p1);               // P2 = HI(H2)
    __syncthreads();
    inv_range<false>(AW,  a0, BW,  b0, b1);
    inv_range<false>(A4W, a0, B4W, b0, b1);
    inv_range<false>(A3W, b0, P3W, p0, p1);               // P3
    __syncthreads();
    inv_range<false>(BW,  b0, P0W, p0, p1);               // P0
    inv_range<false>(B4W, b0, P4W, p0, p1);               // P4
    __syncthreads();

    // ---- final inverse level: s_j on the block's 64 rows ----
    for (int idx = threadIdx.x; idx < 5 * ROWS; idx += 256) {
        int j = idx >> 6;
        int r = idx & (ROWS - 1);
        int l = l0 + r;
        int base = (l >> 1) - p0;
        int odd = l & 1;
        const float* Pj = (j == 0) ? P0W : (j == 1) ? HI1 :
                          (j == 2) ? P2W : (j == 3) ? P3W : P4W;
        bool hi = (j == 1);
        float f0 = odd ? (hi ? c_DH[0] : c_DL[0]) : (hi ? c_DH[1] : c_DL[1]);
        float f1 = odd ? (hi ? c_DH[2] : c_DL[2]) : (hi ? c_DH[3] : c_DL[3]);
        float f2 = odd ? (hi ? c_DH[4] : c_DL[4]) : (hi ? c_DH[5] : c_DL[5]);
        float f3 = odd ? (hi ? c_DH[6] : c_DL[6]) : (hi ? c_DH[7] : c_DL[7]);
        float acc = Pj[base] * f0;
        acc = fmaf(Pj[base + 1], f1, acc);
        acc = fmaf(Pj[base + 2], f2, acc);
        acc = fmaf(Pj[base + 3], f3, acc);
        SJ[idx] = acc;
    }
    __syncthreads();

    // ---- rank-5 expansion, nontemporal stores ----
    int half = threadIdx.x >> 7;       // which row of each pair
    int c4 = threadIdx.x & 127;        // float4 index over 512 channels
    f32x4 g0 = ((const f32x4*)(GL + 0 * DM))[c4];
    f32x4 g1 = ((const f32x4*)(GL + 1 * DM))[c4];
    f32x4 g2 = ((const f32x4*)(GL + 2 * DM))[c4];
    f32x4 g3 = ((const f32x4*)(GL + 3 * DM))[c4];
    f32x4 g4 = ((const f32x4*)(GL + 4 * DM))[c4];

    size_t rowbase = (size_t)b * LSEQ + l0;
#pragma unroll 4
    for (int r = 0; r < ROWS / 2; ++r) {
        int rr = r * 2 + half;
        float s0 = SJ[rr];
        float s1 = SJ[64 + rr];
        float s2 = SJ[128 + rr];
        float s3 = SJ[192 + rr];
        float s4 = SJ[256 + rr];
        f32x4 acc;
        acc.x = fmaf(s4, g4.x, fmaf(s3, g3.x, fmaf(s2, g2.x, fmaf(s1, g1.x, s0 * g0.x))));
        acc.y = fmaf(s4, g4.y, fmaf(s3, g3.y, fmaf(s2, g2.y, fmaf(s1, g1.y, s0 * g0.y))));
        acc.z = fmaf(s4, g4.z, fmaf(s3, g3.z, fmaf(s2, g2.z, fmaf(s1, g1.z, s0 * g0.z))));
        acc.w = fmaf(s4, g4.w, fmaf(s3, g3.w, fmaf(s2, g2.w, fmaf(s1, g1.w, s0 * g0.w))));
        __builtin_nontemporal_store(acc, (f32x4*)out + (rowbase + rr) * (DM / 4) + c4);
    }
}

extern "C" void kernel_launch(void* const* d_in, const int* in_sizes, int n_in,
                              void* d_out, int out_size, void* d_ws, size_t ws_size,
                              hipStream_t stream) {
    const float* x         = (const float*)d_in[0];
    const float* proj_w    = (const float*)d_in[1];
    const float* proj_b    = (const float*)d_in[2];
    const float* scale_emb = (const float*)d_in[3];
    const float* gate_w    = (const float*)d_in[4];
    const float* gate_b    = (const float*)d_in[5];
    float* out   = (float*)d_out;
    float* gates = (float*)d_ws;     // 5*512 floats

    gates_kernel<<<32, 1024, 0, stream>>>(scale_emb, gate_w, gate_b, gates);
    fused_kernel<<<NB * CHUNKS, 256, 0, stream>>>(x, proj_w, proj_b, gates, out);
}